// Round 1
// baseline (11228.281 us; speedup 1.0000x reference)
//
#include <hip/hip_runtime.h>
#include <hip/hip_cooperative_groups.h>

namespace cg = cooperative_groups;

typedef unsigned short u16;
typedef unsigned int u32;
typedef __bf16 bf16x8 __attribute__((ext_vector_type(8)));
typedef float f32x4 __attribute__((ext_vector_type(4)));

#define B_ 256
#define T_ 128
#define E_ 300
#define EP 320
#define H_ 2048
#define G_ 8192

// ws layout (bytes)
#define OFF_XBF   0UL
#define OFF_WIH   20971520UL
#define OFF_WHH   26214400UL
#define OFF_BIAS  59768832UL
#define OFF_HBUF  59801600UL

#define GLDS16(gp, sp)                                                    \
  __builtin_amdgcn_global_load_lds(                                       \
      (__attribute__((address_space(1))) void*)(void*)(gp),               \
      (__attribute__((address_space(3))) void*)(sp), 16, 0, 0)

__device__ __forceinline__ u16 f2bf(float f) {
  u32 u = __builtin_bit_cast(u32, f);
  return (u16)((u + 0x7FFFu + ((u >> 16) & 1u)) >> 16);
}
__device__ __forceinline__ float sigm_f(float x) {
  return __builtin_amdgcn_rcpf(1.0f + __expf(-x));
}
__device__ __forceinline__ float tanh_f(float x) {
  // 1 - 2/(1+e^{2x}); saturates correctly at +/-inf of exp
  return 1.0f - 2.0f * __builtin_amdgcn_rcpf(1.0f + __expf(2.0f * x));
}

// ---------------- prep: pack/convert everything to bf16, zero h ----------------
__global__ void prep_kernel(const float* __restrict__ x, const float* __restrict__ Wih,
                            const float* __restrict__ Whh, const float* __restrict__ bih,
                            const float* __restrict__ bhh, u16* __restrict__ xbf,
                            u16* __restrict__ wihb, u16* __restrict__ whhb,
                            float* __restrict__ biasc, u16* __restrict__ hbuf) {
  const long NX = (long)T_ * B_ * EP;      // 10,485,760
  const long NWIH = (long)G_ * EP;         // 2,621,440
  const long NWHH = (long)G_ * H_;         // 16,777,216
  const long NBS = G_;
  const long NH = 2L * B_ * H_;            // 1,048,576
  const long total = NX + NWIH + NWHH + NBS + NH;
  for (long q = (long)blockIdx.x * blockDim.x + threadIdx.x; q < total;
       q += (long)gridDim.x * blockDim.x) {
    long r = q;
    if (r < NX) {
      int t = (int)(r / (B_ * EP));
      int rem = (int)(r % (B_ * EP));
      int b = rem / EP, e = rem % EP;
      float v = (e < E_) ? x[((long)b * T_ + t) * E_ + e] : 0.0f;
      xbf[r] = f2bf(v);
    } else if ((r -= NX) < NWIH) {
      int n = (int)(r / EP), e = (int)(r % EP);
      wihb[r] = f2bf((e < E_) ? Wih[(long)n * E_ + e] : 0.0f);
    } else if ((r -= NWIH) < NWHH) {
      whhb[r] = f2bf(Whh[r]);   // W_hh is [8192,2048] row-major == B^T layout already
    } else if ((r -= NWHH) < NBS) {
      biasc[r] = bih[r] + bhh[r];
    } else {
      r -= NBS;
      hbuf[r] = 0;
    }
  }
}

// ---------------- main cooperative LSTM kernel ----------------
// grid 256 blocks x 256 thr. Block bid: b0=(bid&1)*128 batch rows, j0=(bid>>1)*16 h-cols.
// Per step: gates[128 x (4 gates x 16)] = h@Whh^T + x_t@Wih^T, MFMA 16x16x32 bf16.
// K phases: k in [0,32) -> h (K=2048), k in [32,37) -> x (K=320 padded).
__global__ void __launch_bounds__(256, 1)
lstm_kernel(const u16* __restrict__ xbf, const u16* __restrict__ wihb,
            const u16* __restrict__ whhb, const float* __restrict__ biasc,
            u16* __restrict__ hbuf, float* __restrict__ out) {
  __shared__ __align__(16) u16 As[2][128 * 64];   // A tiles: 128 rows x 64 k
  __shared__ __align__(16) u16 Bs[2][64 * 64];    // B tiles: 64 n x 64 k

  const int tid = threadIdx.x;
  const int l = tid & 63;
  const int w = tid >> 6;
  const int bid = blockIdx.x;
  const int b0 = (bid & 1) * 128;
  const int j0 = (bid >> 1) * 16;

  // C/D layout (m89): col = lane&15, row = (lane>>4)*4 + reg. All 4 gates same lane.
  const int jc = j0 + (l & 15);
  const float bi = biasc[jc];
  const float bf_ = biasc[H_ + jc];
  const float bg = biasc[2 * H_ + jc];
  const float bo = biasc[3 * H_ + jc];

  float cst[2][4];
#pragma unroll
  for (int mi = 0; mi < 2; ++mi)
#pragma unroll
    for (int r = 0; r < 4; ++r) cst[mi][r] = 0.0f;

  cg::grid_group grid = cg::this_grid();

  for (int t = 0; t < T_; ++t) {
    const u16* hcur = hbuf + (size_t)(t & 1) * (B_ * H_) + (size_t)b0 * H_;
    u16* hnxt = hbuf + (size_t)((t + 1) & 1) * (B_ * H_);
    const u16* xsrc = xbf + (size_t)t * (B_ * EP) + (size_t)b0 * EP;

    f32x4 acc[2][4];
#pragma unroll
    for (int mi = 0; mi < 2; ++mi)
#pragma unroll
      for (int ni = 0; ni < 4; ++ni) acc[mi][ni] = (f32x4){0.f, 0.f, 0.f, 0.f};

    // async stage K-chunk k into LDS buffer (k&1)
    auto stage = [&](int k) {
      const u16 *sA, *sB;
      int strA, strB, kk;
      if (k < 32) { kk = k << 6; sA = hcur; strA = H_; sB = whhb; strB = H_; }
      else        { kk = (k - 32) << 6; sA = xsrc; strA = EP; sB = wihb; strB = EP; }
      u16* Ad = &As[k & 1][w * 512];   // wave-uniform LDS base; HW scatters lane*16B
      u16* Bd = &Bs[k & 1][w * 512];
#pragma unroll
      for (int i = 0; i < 4; ++i) {    // A: 16KB = 4 issues of 256 thr x 16B
        int ii = i * 256 + tid;
        const u16* g = sA + (size_t)(ii >> 3) * strA + kk + (ii & 7) * 8;
        GLDS16(g, Ad + i * 2048);
      }
#pragma unroll
      for (int i = 0; i < 2; ++i) {    // B: 8KB = 2 issues
        int ii = i * 256 + tid;
        int nl = ii >> 3;              // 0..63 = [i|f|g|o] x 16 cols
        const u16* g =
            sB + (size_t)((nl >> 4) * H_ + j0 + (nl & 15)) * strB + kk + (ii & 7) * 8;
        GLDS16(g, Bd + i * 2048);
      }
    };

    auto compute = [&](int cur) {
#pragma unroll
      for (int k2 = 0; k2 < 2; ++k2) {
        const u16* ap = &As[cur][(w * 32 + (l & 15)) * 64 + k2 * 32 + (l >> 4) * 8];
        bf16x8 a0 = *(const bf16x8*)ap;
        bf16x8 a1 = *(const bf16x8*)(ap + 16 * 64);
        const u16* bp = &Bs[cur][(l & 15) * 64 + k2 * 32 + (l >> 4) * 8];
        bf16x8 bv0 = *(const bf16x8*)bp;
        bf16x8 bv1 = *(const bf16x8*)(bp + 16 * 64);
        bf16x8 bv2 = *(const bf16x8*)(bp + 32 * 64);
        bf16x8 bv3 = *(const bf16x8*)(bp + 48 * 64);
        acc[0][0] = __builtin_amdgcn_mfma_f32_16x16x32_bf16(a0, bv0, acc[0][0], 0, 0, 0);
        acc[0][1] = __builtin_amdgcn_mfma_f32_16x16x32_bf16(a0, bv1, acc[0][1], 0, 0, 0);
        acc[0][2] = __builtin_amdgcn_mfma_f32_16x16x32_bf16(a0, bv2, acc[0][2], 0, 0, 0);
        acc[0][3] = __builtin_amdgcn_mfma_f32_16x16x32_bf16(a0, bv3, acc[0][3], 0, 0, 0);
        acc[1][0] = __builtin_amdgcn_mfma_f32_16x16x32_bf16(a1, bv0, acc[1][0], 0, 0, 0);
        acc[1][1] = __builtin_amdgcn_mfma_f32_16x16x32_bf16(a1, bv1, acc[1][1], 0, 0, 0);
        acc[1][2] = __builtin_amdgcn_mfma_f32_16x16x32_bf16(a1, bv2, acc[1][2], 0, 0, 0);
        acc[1][3] = __builtin_amdgcn_mfma_f32_16x16x32_bf16(a1, bv3, acc[1][3], 0, 0, 0);
      }
    };

    const int kstart = (t == 0) ? 32 : 0;  // h==0 at t=0: skip Whh phase
    stage(kstart);
    __syncthreads();
    for (int k = kstart; k < 37; ++k) {
      if (k + 1 < 37) stage(k + 1);        // prefetch into other buffer (overlaps MFMA)
      compute(k & 1);
      __syncthreads();                     // drains vmcnt -> next buffer ready
    }

    // lane-local LSTM pointwise update; c lives in registers across all steps
#pragma unroll
    for (int mi = 0; mi < 2; ++mi) {
#pragma unroll
      for (int r = 0; r < 4; ++r) {
        float ig = sigm_f(acc[mi][0][r] + bi);
        float fg = sigm_f(acc[mi][1][r] + bf_);
        float gg = tanh_f(acc[mi][2][r] + bg);
        float og = sigm_f(acc[mi][3][r] + bo);
        float c = fg * cst[mi][r] + ig * gg;
        cst[mi][r] = c;
        float h = og * tanh_f(c);
        int row = b0 + w * 32 + mi * 16 + (l >> 4) * 4 + r;
        hnxt[(size_t)row * H_ + jc] = f2bf(h);
        if (t == T_ - 1) out[(size_t)row * H_ + jc] = h;
      }
    }
    __threadfence();                       // device-scope release of h writes (G16)
    if (t != T_ - 1) grid.sync();
  }
}

extern "C" void kernel_launch(void* const* d_in, const int* in_sizes, int n_in,
                              void* d_out, int out_size, void* d_ws, size_t ws_size,
                              hipStream_t stream) {
  const float* x = (const float*)d_in[0];
  const float* Wih = (const float*)d_in[1];
  const float* Whh = (const float*)d_in[2];
  const float* bih = (const float*)d_in[3];
  const float* bhh = (const float*)d_in[4];
  char* ws = (char*)d_ws;
  u16* xbf = (u16*)(ws + OFF_XBF);
  u16* wihb = (u16*)(ws + OFF_WIH);
  u16* whhb = (u16*)(ws + OFF_WHH);
  float* biasc = (float*)(ws + OFF_BIAS);
  u16* hbuf = (u16*)(ws + OFF_HBUF);
  float* out = (float*)d_out;

  hipLaunchKernelGGL(prep_kernel, dim3(2048), dim3(256), 0, stream,
                     x, Wih, Whh, bih, bhh, xbf, wihb, whhb, biasc, hbuf);

  void* args[] = {(void*)&xbf, (void*)&wihb, (void*)&whhb,
                  (void*)&biasc, (void*)&hbuf, (void*)&out};
  hipLaunchCooperativeKernel((void*)lstm_kernel, dim3(256), dim3(256), args, 0, stream);
}

// Round 2
// 3783.421 us; speedup vs baseline: 2.9678x; 2.9678x over previous
//
#include <hip/hip_runtime.h>

typedef unsigned short u16;
typedef unsigned int u32;
typedef __bf16 bf16x8 __attribute__((ext_vector_type(8)));
typedef float f32x4 __attribute__((ext_vector_type(4)));

#define B_ 256
#define T_ 128
#define E_ 300
#define EP 320
#define H_ 2048
#define G_ 8192

// ws layout (bytes)
#define OFF_XBF   0UL
#define OFF_WIH   20971520UL
#define OFF_WHH   26214400UL
#define OFF_BIAS  59768832UL
#define OFF_HBUF  59801600UL
#define OFF_BAR   61898752UL

// plain global->LDS (L2-cacheable: weights, x)
#define GLDS16(gp, sp)                                                    \
  __builtin_amdgcn_global_load_lds(                                       \
      (__attribute__((address_space(1))) void*)(void*)(gp),               \
      (__attribute__((address_space(3))) void*)(sp), 16, 0, 0)
// device-coherent global->LDS (sc0|sc1 = 1|16: bypass L1+L2) for h
#define GLDS16C(gp, sp)                                                   \
  __builtin_amdgcn_global_load_lds(                                       \
      (__attribute__((address_space(1))) void*)(void*)(gp),               \
      (__attribute__((address_space(3))) void*)(sp), 16, 0, 17)

__device__ __forceinline__ u16 f2bf(float f) {
  u32 u = __builtin_bit_cast(u32, f);
  return (u16)((u + 0x7FFFu + ((u >> 16) & 1u)) >> 16);
}
__device__ __forceinline__ float sigm_f(float x) {
  return __builtin_amdgcn_rcpf(1.0f + __expf(-x));
}
__device__ __forceinline__ float tanh_f(float x) {
  return 1.0f - 2.0f * __builtin_amdgcn_rcpf(1.0f + __expf(2.0f * x));
}

// ---------------- prep: pack/convert to bf16, zero barrier flags ----------------
__global__ void prep_kernel(const float* __restrict__ x, const float* __restrict__ Wih,
                            const float* __restrict__ Whh, const float* __restrict__ bih,
                            const float* __restrict__ bhh, u16* __restrict__ xbf,
                            u16* __restrict__ wihb, u16* __restrict__ whhb,
                            float* __restrict__ biasc, u32* __restrict__ bar) {
  const long NX = (long)T_ * B_ * EP;
  const long NWIH = (long)G_ * EP;
  const long NWHH = (long)G_ * H_;
  const long NBS = G_;
  const long NBAR = T_;
  const long total = NX + NWIH + NWHH + NBS + NBAR;
  for (long q = (long)blockIdx.x * blockDim.x + threadIdx.x; q < total;
       q += (long)gridDim.x * blockDim.x) {
    long r = q;
    if (r < NX) {
      int t = (int)(r / (B_ * EP));
      int rem = (int)(r % (B_ * EP));
      int b = rem / EP, e = rem % EP;
      float v = (e < E_) ? x[((long)b * T_ + t) * E_ + e] : 0.0f;
      xbf[r] = f2bf(v);
    } else if ((r -= NX) < NWIH) {
      int n = (int)(r / EP), e = (int)(r % EP);
      wihb[r] = f2bf((e < E_) ? Wih[(long)n * E_ + e] : 0.0f);
    } else if ((r -= NWIH) < NWHH) {
      whhb[r] = f2bf(Whh[r]);   // [8192,2048] row-major == B^T layout
    } else if ((r -= NWHH) < NBS) {
      biasc[r] = bih[r] + bhh[r];
    } else {
      r -= NBS;
      bar[r] = 0;               // visible after kernel-end flush
    }
  }
}

// ---------------- main persistent LSTM kernel ----------------
// 256 blocks x 256 thr, 1 block/CU. Block: 64 batch rows x (32 j-cols x 4 gates).
// gb = bid>>6 (batch grp), gn = bid&63 (col grp) -> the 4 gb-siblings of a gn
// share bid%8, i.e. the same XCD: W slice (606KB) fetched once per XCD, stays in L2.
// Custom relaxed barrier (no fences => no L2 invalidate). h crosses XCDs via
// sc0sc1 stores + sc0sc1 loads (L2-bypass, coherent at L3).
__global__ void __launch_bounds__(256, 1)
lstm_kernel(const u16* __restrict__ xbf, const u16* __restrict__ wihb,
            const u16* __restrict__ whhb, const float* __restrict__ biasc,
            u16* __restrict__ hbuf, u32* __restrict__ bar, float* __restrict__ out) {
  __shared__ __align__(16) u16 As[2][64 * 64];    // 16 KB: A tile 64 rows x 64 k
  __shared__ __align__(16) u16 Bs[2][128 * 64];   // 32 KB: B tile 128 n x 64 k

  const int tid = threadIdx.x;
  const int l = tid & 63;
  const int w = tid >> 6;
  const int wr = w >> 1, wj = w & 1;       // wave tile: 32 rows x (16 j x 4 gates)
  const int bid = blockIdx.x;
  const int b0 = (bid >> 6) << 6;
  const int j0 = (bid & 63) << 5;
  const int jc = j0 + (wj << 4) + (l & 15);
  // XOR-swizzle: LDS slot (row, c) holds global chunk c ^ (row&7); conflict-free b128.
  const int cgl = (tid & 7) ^ ((tid >> 3) & 7);

  const float bi = biasc[jc];
  const float bff = biasc[2048 + jc];
  const float bg = biasc[4096 + jc];
  const float bo = biasc[6144 + jc];

  float cst[2][4];
#pragma unroll
  for (int mi = 0; mi < 2; ++mi)
#pragma unroll
    for (int r = 0; r < 4; ++r) cst[mi][r] = 0.0f;

  // A: 8 KB = 2 issues x 256 thr x 16 B ; rows are batch-local 0..63
  auto stageA = [&](const u16* srcA, int strA, int kk, int p, bool coh) {
    u16* Ad = &As[p][w * 512];
#pragma unroll
    for (int i = 0; i < 2; ++i) {
      int slot = i * 256 + tid;
      const u16* g = srcA + (size_t)(slot >> 3) * strA + kk + cgl * 8;
      if (coh) { GLDS16C(g, Ad + i * 2048); } else { GLDS16(g, Ad + i * 2048); }
    }
  };
  // B: 16 KB = 4 issues ; LDS row nl = gate*32 + jj -> global row gate*2048 + j0 + jj
  auto stageB = [&](const u16* srcB, int strB, int kk, int p) {
    u16* Bd = &Bs[p][w * 512];
#pragma unroll
    for (int i = 0; i < 4; ++i) {
      int slot = i * 256 + tid;
      int nl = slot >> 3;
      int grow = ((nl >> 5) << 11) + j0 + (nl & 31);
      const u16* g = srcB + (size_t)grow * strB + kk + cgl * 8;
      GLDS16(g, Bd + i * 2048);
    }
  };

#pragma unroll 1
  for (int t = 0; t < T_; ++t) {
    const u16* hcur = hbuf + (size_t)(t & 1) * (B_ * H_) + (size_t)b0 * H_;
    u16* hnxt = hbuf + (size_t)((t + 1) & 1) * (B_ * H_);
    const u16* xsrc = xbf + (size_t)t * (B_ * EP) + (size_t)b0 * EP;

    f32x4 acc[2][4];
#pragma unroll
    for (int mi = 0; mi < 2; ++mi)
#pragma unroll
      for (int g = 0; g < 4; ++g) acc[mi][g] = (f32x4){0.f, 0.f, 0.f, 0.f};

    auto compute = [&](int p) {
#pragma unroll
      for (int k2 = 0; k2 < 2; ++k2) {
        int cp = ((k2 << 2) + (l >> 4)) ^ (l & 7);    // swizzled chunk (row&7 == l&7)
        const u16* ap = &As[p][((wr << 5) + (l & 15)) * 64 + cp * 8];
        bf16x8 a0 = *(const bf16x8*)ap;
        bf16x8 a1 = *(const bf16x8*)(ap + 1024);      // +16 rows
        const u16* bp = &Bs[p][((wj << 4) + (l & 15)) * 64 + cp * 8];
        bf16x8 bv0 = *(const bf16x8*)bp;
        bf16x8 bv1 = *(const bf16x8*)(bp + 2048);     // +32 n-rows = next gate
        bf16x8 bv2 = *(const bf16x8*)(bp + 4096);
        bf16x8 bv3 = *(const bf16x8*)(bp + 6144);
        acc[0][0] = __builtin_amdgcn_mfma_f32_16x16x32_bf16(a0, bv0, acc[0][0], 0, 0, 0);
        acc[0][1] = __builtin_amdgcn_mfma_f32_16x16x32_bf16(a0, bv1, acc[0][1], 0, 0, 0);
        acc[0][2] = __builtin_amdgcn_mfma_f32_16x16x32_bf16(a0, bv2, acc[0][2], 0, 0, 0);
        acc[0][3] = __builtin_amdgcn_mfma_f32_16x16x32_bf16(a0, bv3, acc[0][3], 0, 0, 0);
        acc[1][0] = __builtin_amdgcn_mfma_f32_16x16x32_bf16(a1, bv0, acc[1][0], 0, 0, 0);
        acc[1][1] = __builtin_amdgcn_mfma_f32_16x16x32_bf16(a1, bv1, acc[1][1], 0, 0, 0);
        acc[1][2] = __builtin_amdgcn_mfma_f32_16x16x32_bf16(a1, bv2, acc[1][2], 0, 0, 0);
        acc[1][3] = __builtin_amdgcn_mfma_f32_16x16x32_bf16(a1, bv3, acc[1][3], 0, 0, 0);
      }
    };

    // ---- x phase (no h dependency): runs BEFORE barrier wait, hides skew
    int p = 0;
    stageA(xsrc, EP, 0, 0, false);
    stageB(wihb, EP, 0, 0);
    __syncthreads();
#pragma unroll 1
    for (int kx = 0; kx < 5; ++kx) {
      if (kx < 4) {
        stageA(xsrc, EP, (kx + 1) << 6, p ^ 1, false);
        stageB(wihb, EP, (kx + 1) << 6, p ^ 1);
      }
      compute(p);
      __syncthreads();
      p ^= 1;
    }

    // ---- h phase (skipped at t=0: h==0)
    if (t > 0) {
      if (tid == 0) {
        while (__hip_atomic_load(&bar[t - 1], __ATOMIC_RELAXED,
                                 __HIP_MEMORY_SCOPE_AGENT) < 256u)
          __builtin_amdgcn_s_sleep(2);
      }
      __syncthreads();
      stageA(hcur, H_, 0, p, true);
      stageB(whhb, H_, 0, p);
      __syncthreads();
#pragma unroll 1
      for (int kh = 0; kh < 32; ++kh) {
        if (kh < 31) {
          stageA(hcur, H_, (kh + 1) << 6, p ^ 1, true);
          stageB(whhb, H_, (kh + 1) << 6, p ^ 1);
        }
        compute(p);
        __syncthreads();
        p ^= 1;
      }
    }

    // ---- lane-local LSTM pointwise; c stays in registers across steps
#pragma unroll
    for (int mi = 0; mi < 2; ++mi) {
#pragma unroll
      for (int r = 0; r < 4; ++r) {
        float ig = sigm_f(acc[mi][0][r] + bi);
        float fg = sigm_f(acc[mi][1][r] + bff);
        float gg = tanh_f(acc[mi][2][r] + bg);
        float og = sigm_f(acc[mi][3][r] + bo);
        float c = fg * cst[mi][r] + ig * gg;
        cst[mi][r] = c;
        float h = og * tanh_f(c);
        int row = b0 + (wr << 5) + (mi << 4) + ((l >> 4) << 2) + r;
        if (t < T_ - 1) {
          u16 hv = f2bf(h);
          u16* hp = hnxt + (size_t)row * H_ + jc;
          asm volatile("global_store_short %0, %1, off sc0 sc1"
                       :: "v"(hp), "v"((u32)hv) : "memory");
        } else {
          out[(size_t)row * H_ + jc] = h;
        }
      }
    }

    if (t < T_ - 1) {
      __builtin_amdgcn_s_waitcnt(0);      // h stores reached coherent point
      __syncthreads();                    // all 4 waves drained
      if (tid == 0)
        __hip_atomic_fetch_add(&bar[t], 1u, __ATOMIC_RELAXED,
                               __HIP_MEMORY_SCOPE_AGENT);
    }
  }
}

extern "C" void kernel_launch(void* const* d_in, const int* in_sizes, int n_in,
                              void* d_out, int out_size, void* d_ws, size_t ws_size,
                              hipStream_t stream) {
  const float* x = (const float*)d_in[0];
  const float* Wih = (const float*)d_in[1];
  const float* Whh = (const float*)d_in[2];
  const float* bih = (const float*)d_in[3];
  const float* bhh = (const float*)d_in[4];
  char* ws = (char*)d_ws;
  u16* xbf = (u16*)(ws + OFF_XBF);
  u16* wihb = (u16*)(ws + OFF_WIH);
  u16* whhb = (u16*)(ws + OFF_WHH);
  float* biasc = (float*)(ws + OFF_BIAS);
  u16* hbuf = (u16*)(ws + OFF_HBUF);
  u32* bar = (u32*)(ws + OFF_BAR);
  float* out = (float*)d_out;

  hipLaunchKernelGGL(prep_kernel, dim3(2048), dim3(256), 0, stream,
                     x, Wih, Whh, bih, bhh, xbf, wihb, whhb, biasc, bar);

  void* args[] = {(void*)&xbf, (void*)&wihb, (void*)&whhb,
                  (void*)&biasc, (void*)&hbuf, (void*)&bar, (void*)&out};
  hipLaunchCooperativeKernel((void*)lstm_kernel, dim3(256), dim3(256), args, 0, stream);
}